// Round 1
// baseline (3208.484 us; speedup 1.0000x reference)
//
#include <hip/hip_runtime.h>

// VarianceAdaptor: B=16, S=512, C(D_MODEL)=F(FILTER)=512, K=3, T(MAX_FRAMES)=2048
#define B_ 16
#define S_ 512
#define C_ 512
#define T_ 2048

// ---------------------------------------------------------------------------
// Pack conv weight (F, C, 3) -> (3, F, C) so GEMM K-chunks are contiguous.
__global__ void pack_w_kernel(const float* __restrict__ w, float* __restrict__ wp) {
    int i = blockIdx.x * 256 + threadIdx.x;   // i over F*C = 262144
    if (i >= C_ * C_) return;
    const float* s = w + (long)i * 3;
    wp[i]           = s[0];
    wp[i + 262144]  = s[1];
    wp[i + 524288]  = s[2];
}

__global__ void rowidx_id_kernel(int* __restrict__ r) {
    int t = blockIdx.x * 256 + threadIdx.x;
    if (t < T_) r[t] = t;
}

// Per batch: cumsum(clamp(D,0)) over S, then rowidx[t] = searchsorted_right(csum,t)
// clamped to S-1, or -1 where t >= min(total, T).
__global__ void expand_rowidx_kernel(const int* __restrict__ Dgt, int* __restrict__ ridx) {
    __shared__ int cs[S_];
    int b = blockIdx.x, s = threadIdx.x;
    int d = Dgt[b * S_ + s];
    cs[s] = d < 0 ? 0 : d;
    __syncthreads();
    for (int off = 1; off < S_; off <<= 1) {
        int v = (s >= off) ? cs[s - off] : 0;
        __syncthreads();
        cs[s] += v;
        __syncthreads();
    }
    int total = cs[S_ - 1];
    int limit = total < T_ ? total : T_;
    for (int t = s; t < T_; t += S_) {
        int lo = 0, hi = S_;
        while (lo < hi) { int mid = (lo + hi) >> 1; if (cs[mid] <= t) lo = mid + 1; else hi = mid; }
        if (lo > S_ - 1) lo = S_ - 1;
        ridx[b * T_ + t] = (t < limit) ? lo : -1;
    }
}

__global__ void fill_kernel(float* __restrict__ dst, int n, const float* __restrict__ v) {
    int i = blockIdx.x * 256 + threadIdx.x;
    if (i < n) dst[i] = v[0];
}

// H_adapted = gather(H via rowidx, 0 where invalid) + P_gt*pw + pb + E_gt*ew + eb
__global__ void adapt_kernel(const float* __restrict__ H, const int* __restrict__ ridx,
                             const float* __restrict__ Pgt, const float* __restrict__ Egt,
                             const float* __restrict__ pw, const float* __restrict__ pb,
                             const float* __restrict__ ew, const float* __restrict__ eb,
                             float* __restrict__ out) {
    int i = blockIdx.x * 256 + threadIdx.x;   // B*T*C/4 = 4,194,304 float4s
    int f4 = i & 127;
    int p  = i >> 7;            // 0..32767 = b*T + t
    int b  = p >> 11;
    int r  = ridx[p];
    float pg = Pgt[p], eg = Egt[p];
    int f = f4 << 2;
    float4 pwv = *(const float4*)(pw + f);
    float4 pbv = *(const float4*)(pb + f);
    float4 ewv = *(const float4*)(ew + f);
    float4 ebv = *(const float4*)(eb + f);
    float4 h = make_float4(0.f, 0.f, 0.f, 0.f);
    if (r >= 0) h = *(const float4*)(H + ((long)b * S_ + r) * C_ + f);
    float4 o;
    o.x = h.x + pg * pwv.x + pbv.x + eg * ewv.x + ebv.x;
    o.y = h.y + pg * pwv.y + pbv.y + eg * ewv.y + ebv.y;
    o.z = h.z + pg * pwv.z + pbv.z + eg * ewv.z + ebv.z;
    o.w = h.w + pg * pwv.w + pbv.w + eg * ewv.w + ebv.w;
    *(float4*)(out + (long)p * C_ + f) = o;
}

// ---------------------------------------------------------------------------
// Conv-as-GEMM: out(p, f) = bias[f] + sum_{tap,c} wp[tap][f][c] * srcrow(p,tap)[c]
// where srcrow(p,tap) = src + b*srcBatch + rowidx[b*ridxStride + t+tap-1]*C_
// (zero row if out of range or rowidx < 0).  Tile 128(pos) x 128(feat) x 16.
// mode 0: dst[p*C_ + f] = relu(...)           (h1 buffer)
// mode 1: atomicAdd(dst[p], sum_f relu(...)*wl[f])  (fused final linear)
#define BN 128
#define BM 128
#define BK 16
#define PAD 132

__global__ __launch_bounds__(256, 2) void conv_gemm_kernel(
    const float* __restrict__ src, long srcBatch,
    const int* __restrict__ rowidx, int ridxStride,
    int Lshift,
    const float* __restrict__ wp,
    const float* __restrict__ bias,
    const float* __restrict__ wl,
    float* __restrict__ dst,
    int mode)
{
    __shared__ float At[BK][PAD];
    __shared__ float Wt[BK][PAD];
    int tid = threadIdx.x;
    int n0 = blockIdx.x * BN;
    int m0 = blockIdx.y * BM;
    int L = 1 << Lshift;
    int tx = tid & 15, ty = tid >> 4;

    float acc[8][8];
#pragma unroll
    for (int i = 0; i < 8; ++i)
#pragma unroll
        for (int j = 0; j < 8; ++j) acc[i][j] = 0.f;

    for (int tap = 0; tap < 3; ++tap) {
        const float* aptr[2];
        bool aval[2];
        const float* wptr[2];
#pragma unroll
        for (int q = 0; q < 2; ++q) {
            int idx = tid + q * 256;          // 0..511
            int row = idx >> 2, seg = idx & 3;
            int p = n0 + row;
            int b = p >> Lshift;
            int t = p & (L - 1);
            int tsrc = t + tap - 1;
            int r = -1;
            if (tsrc >= 0 && tsrc < L) r = rowidx[b * ridxStride + tsrc];
            aval[q] = (r >= 0);
            aptr[q] = src + (long)b * srcBatch + (long)(r < 0 ? 0 : r) * C_ + (seg << 2);
            wptr[q] = wp + (long)tap * (C_ * C_) + (long)(m0 + row) * C_ + (seg << 2);
        }
        for (int c0 = 0; c0 < C_; c0 += BK) {
            __syncthreads();
#pragma unroll
            for (int q = 0; q < 2; ++q) {
                int idx = tid + q * 256;
                int row = idx >> 2, seg = idx & 3;
                float4 av = make_float4(0.f, 0.f, 0.f, 0.f);
                if (aval[q]) av = *(const float4*)(aptr[q] + c0);
                At[(seg << 2) + 0][row] = av.x;
                At[(seg << 2) + 1][row] = av.y;
                At[(seg << 2) + 2][row] = av.z;
                At[(seg << 2) + 3][row] = av.w;
                float4 wv = *(const float4*)(wptr[q] + c0);
                Wt[(seg << 2) + 0][row] = wv.x;
                Wt[(seg << 2) + 1][row] = wv.y;
                Wt[(seg << 2) + 2][row] = wv.z;
                Wt[(seg << 2) + 3][row] = wv.w;
            }
            __syncthreads();
#pragma unroll
            for (int kk = 0; kk < BK; ++kk) {
                float4 a0 = *(const float4*)&At[kk][ty << 3];
                float4 a1 = *(const float4*)&At[kk][(ty << 3) + 4];
                float4 w0 = *(const float4*)&Wt[kk][tx << 3];
                float4 w1 = *(const float4*)&Wt[kk][(tx << 3) + 4];
                float a[8] = {a0.x, a0.y, a0.z, a0.w, a1.x, a1.y, a1.z, a1.w};
                float w[8] = {w0.x, w0.y, w0.z, w0.w, w1.x, w1.y, w1.z, w1.w};
#pragma unroll
                for (int i = 0; i < 8; ++i)
#pragma unroll
                    for (int j = 0; j < 8; ++j)
                        acc[i][j] += a[i] * w[j];
            }
        }
    }

    if (mode == 0) {
#pragma unroll
        for (int i = 0; i < 8; ++i) {
            int p = n0 + (ty << 3) + i;
            int f = m0 + (tx << 3);
            float* drow = dst + (long)p * C_ + f;
            float4 o0, o1;
            o0.x = fmaxf(acc[i][0] + bias[f + 0], 0.f);
            o0.y = fmaxf(acc[i][1] + bias[f + 1], 0.f);
            o0.z = fmaxf(acc[i][2] + bias[f + 2], 0.f);
            o0.w = fmaxf(acc[i][3] + bias[f + 3], 0.f);
            o1.x = fmaxf(acc[i][4] + bias[f + 4], 0.f);
            o1.y = fmaxf(acc[i][5] + bias[f + 5], 0.f);
            o1.z = fmaxf(acc[i][6] + bias[f + 6], 0.f);
            o1.w = fmaxf(acc[i][7] + bias[f + 7], 0.f);
            *(float4*)drow = o0;
            *(float4*)(drow + 4) = o1;
        }
    } else {
        __syncthreads();
        float* red = &At[0][0];   // 128*16 = 2048 floats <= 16*132
#pragma unroll
        for (int i = 0; i < 8; ++i) {
            float s = 0.f;
#pragma unroll
            for (int j = 0; j < 8; ++j) {
                int f = m0 + (tx << 3) + j;
                s += fmaxf(acc[i][j] + bias[f], 0.f) * wl[f];
            }
            red[((ty << 3) + i) * 16 + tx] = s;
        }
        __syncthreads();
        if (tid < 128) {
            float s = 0.f;
#pragma unroll
            for (int x = 0; x < 16; ++x) s += red[tid * 16 + x];
            atomicAdd(dst + n0 + tid, s);
        }
    }
}

// ---------------------------------------------------------------------------
extern "C" void kernel_launch(void* const* d_in, const int* in_sizes, int n_in,
                              void* d_out, int out_size, void* d_ws, size_t ws_size,
                              hipStream_t stream) {
    const float* H    = (const float*)d_in[0];
    const int*   Dgt  = (const int*)d_in[1];
    const float* Pgt  = (const float*)d_in[2];
    const float* Egt  = (const float*)d_in[3];
    const float* dp_w1 = (const float*)d_in[4];
    const float* dp_b1 = (const float*)d_in[5];
    const float* dp_w2 = (const float*)d_in[6];
    const float* dp_b2 = (const float*)d_in[7];
    const float* dp_wl = (const float*)d_in[8];
    const float* dp_bl = (const float*)d_in[9];
    const float* pp_w1 = (const float*)d_in[10];
    const float* pp_b1 = (const float*)d_in[11];
    const float* pp_w2 = (const float*)d_in[12];
    const float* pp_b2 = (const float*)d_in[13];
    const float* pp_wl = (const float*)d_in[14];
    const float* pp_bl = (const float*)d_in[15];
    const float* ep_w1 = (const float*)d_in[16];
    const float* ep_b1 = (const float*)d_in[17];
    const float* ep_w2 = (const float*)d_in[18];
    const float* ep_b2 = (const float*)d_in[19];
    const float* ep_wl = (const float*)d_in[20];
    const float* ep_bl = (const float*)d_in[21];
    const float* pitch_w  = (const float*)d_in[22];
    const float* pitch_b  = (const float*)d_in[23];
    const float* energy_w = (const float*)d_in[24];
    const float* energy_b = (const float*)d_in[25];

    float* out     = (float*)d_out;
    float* H_adapt = out;                       // 16*2048*512 = 16,777,216
    float* D_pred  = out + 16777216;            // 16*512 = 8192
    float* P_pred  = out + 16785408;            // 16*2048 = 32768
    float* E_pred  = out + 16818176;            // 16*2048 = 32768

    char* ws = (char*)d_ws;
    float* wpack = (float*)ws;                  // 6 * 786432 floats = 18.9 MB
    size_t off = 6UL * 786432UL * 4UL;
    int* ridx_id  = (int*)(ws + off); off += 2048 * 4;
    int* ridx_exp = (int*)(ws + off); off += (size_t)B_ * T_ * 4;
    off = (off + 255) & ~(size_t)255;
    float* h1 = (float*)(ws + off);             // 16*2048*512 floats = 67 MB

    // Pack all six conv weights
    hipLaunchKernelGGL(pack_w_kernel, dim3(1024), dim3(256), 0, stream, dp_w1, wpack + 0UL * 786432);
    hipLaunchKernelGGL(pack_w_kernel, dim3(1024), dim3(256), 0, stream, dp_w2, wpack + 1UL * 786432);
    hipLaunchKernelGGL(pack_w_kernel, dim3(1024), dim3(256), 0, stream, pp_w1, wpack + 2UL * 786432);
    hipLaunchKernelGGL(pack_w_kernel, dim3(1024), dim3(256), 0, stream, pp_w2, wpack + 3UL * 786432);
    hipLaunchKernelGGL(pack_w_kernel, dim3(1024), dim3(256), 0, stream, ep_w1, wpack + 4UL * 786432);
    hipLaunchKernelGGL(pack_w_kernel, dim3(1024), dim3(256), 0, stream, ep_w2, wpack + 5UL * 786432);

    hipLaunchKernelGGL(rowidx_id_kernel, dim3(8), dim3(256), 0, stream, ridx_id);
    hipLaunchKernelGGL(expand_rowidx_kernel, dim3(B_), dim3(S_), 0, stream, Dgt, ridx_exp);

    // H_adapted (independent of predictors)
    hipLaunchKernelGGL(adapt_kernel, dim3(16384), dim3(256), 0, stream,
                       H, ridx_exp, Pgt, Egt, pitch_w, pitch_b, energy_w, energy_b, H_adapt);

    // Init predictor outputs with final bias (atomic accumulation target)
    hipLaunchKernelGGL(fill_kernel, dim3(32), dim3(256), 0, stream, D_pred, 8192, dp_bl);
    hipLaunchKernelGGL(fill_kernel, dim3(128), dim3(256), 0, stream, P_pred, 32768, pp_bl);
    hipLaunchKernelGGL(fill_kernel, dim3(128), dim3(256), 0, stream, E_pred, 32768, ep_bl);

    const long hb = (long)S_ * C_;      // H batch stride
    // Duration predictor on H (L=512, Lshift=9)
    hipLaunchKernelGGL(conv_gemm_kernel, dim3(64, 4), dim3(256), 0, stream,
                       H, hb, ridx_id, 0, 9, wpack + 0UL * 786432, dp_b1, (const float*)nullptr, h1, 0);
    hipLaunchKernelGGL(conv_gemm_kernel, dim3(64, 4), dim3(256), 0, stream,
                       h1, (long)512 * C_, ridx_id, 0, 9, wpack + 1UL * 786432, dp_b2, dp_wl, D_pred, 1);

    // Pitch predictor on H_exp (gathered via ridx_exp; L=2048, Lshift=11)
    hipLaunchKernelGGL(conv_gemm_kernel, dim3(256, 4), dim3(256), 0, stream,
                       H, hb, ridx_exp, T_, 11, wpack + 2UL * 786432, pp_b1, (const float*)nullptr, h1, 0);
    hipLaunchKernelGGL(conv_gemm_kernel, dim3(256, 4), dim3(256), 0, stream,
                       h1, (long)T_ * C_, ridx_id, 0, 11, wpack + 3UL * 786432, pp_b2, pp_wl, P_pred, 1);

    // Energy predictor on H_exp
    hipLaunchKernelGGL(conv_gemm_kernel, dim3(256, 4), dim3(256), 0, stream,
                       H, hb, ridx_exp, T_, 11, wpack + 4UL * 786432, ep_b1, (const float*)nullptr, h1, 0);
    hipLaunchKernelGGL(conv_gemm_kernel, dim3(256, 4), dim3(256), 0, stream,
                       h1, (long)T_ * C_, ridx_id, 0, 11, wpack + 5UL * 786432, ep_b2, ep_wl, E_pred, 1);
}

// Round 2
// 480.675 us; speedup vs baseline: 6.6750x; 6.6750x over previous
//
#include <hip/hip_runtime.h>

// VarianceAdaptor: B=16, S=512, C(D_MODEL)=F(FILTER)=512, K=3, T(MAX_FRAMES)=2048
#define B_ 16
#define S_ 512
#define C_ 512
#define T_ 2048

typedef __attribute__((ext_vector_type(8))) short short8;
typedef __attribute__((ext_vector_type(4))) float floatx4;

__device__ __forceinline__ unsigned short f2bf(float x) {
    union { float f; unsigned u; } c; c.f = x;
    unsigned r = (c.u + 0x7fffu + ((c.u >> 16) & 1u)) >> 16;
    return (unsigned short)r;
}

// async global->LDS, 16B per lane; lds dest = wave-uniform base + lane*16
__device__ __forceinline__ void gld_lds16(void* l, const void* g) {
    __builtin_amdgcn_global_load_lds(
        (const __attribute__((address_space(1))) void*)g,
        (__attribute__((address_space(3))) void*)l, 16, 0, 0);
}

// ---------------------------------------------------------------------------
// Pack conv weight (F, C, 3) fp32 -> (3, F, C) bf16 so GEMM K-chunks are contiguous.
__global__ void pack_w_bf16_kernel(const float* __restrict__ w, unsigned short* __restrict__ wp) {
    int i = blockIdx.x * 256 + threadIdx.x;   // i over F*C = 262144
    if (i >= C_ * C_) return;
    const float* s = w + (long)i * 3;
    wp[i]           = f2bf(s[0]);
    wp[i + 262144]  = f2bf(s[1]);
    wp[i + 524288]  = f2bf(s[2]);
}

// fp32 -> bf16 cast, 4 elems/thread
__global__ void cvt_bf16_kernel(const float* __restrict__ x, unsigned short* __restrict__ y, int n4) {
    int i = blockIdx.x * 256 + threadIdx.x;
    if (i >= n4) return;
    float4 v = *(const float4*)(x + (long)i * 4);
    ushort4 o;
    o.x = f2bf(v.x); o.y = f2bf(v.y); o.z = f2bf(v.z); o.w = f2bf(v.w);
    *(ushort4*)(y + (long)i * 4) = o;
}

__global__ void zrow_kernel(unsigned short* __restrict__ z) {
    z[blockIdx.x * 256 + threadIdx.x] = 0;   // grid(2) x 256 = 512 bf16 zeros
}

// Per batch: cumsum(clamp(D,0)) over S, then rowidx[t] = searchsorted_right(csum,t)
// clamped to S-1, or -1 where t >= min(total, T).
__global__ void expand_rowidx_kernel(const int* __restrict__ Dgt, int* __restrict__ ridx) {
    __shared__ int cs[S_];
    int b = blockIdx.x, s = threadIdx.x;
    int d = Dgt[b * S_ + s];
    cs[s] = d < 0 ? 0 : d;
    __syncthreads();
    for (int off = 1; off < S_; off <<= 1) {
        int v = (s >= off) ? cs[s - off] : 0;
        __syncthreads();
        cs[s] += v;
        __syncthreads();
    }
    int total = cs[S_ - 1];
    int limit = total < T_ ? total : T_;
    for (int t = s; t < T_; t += S_) {
        int lo = 0, hi = S_;
        while (lo < hi) { int mid = (lo + hi) >> 1; if (cs[mid] <= t) lo = mid + 1; else hi = mid; }
        if (lo > S_ - 1) lo = S_ - 1;
        ridx[b * T_ + t] = (t < limit) ? lo : -1;
    }
}

__global__ void fill_kernel(float* __restrict__ dst, int n, const float* __restrict__ v) {
    int i = blockIdx.x * 256 + threadIdx.x;
    if (i < n) dst[i] = v[0];
}

// H_adapted = gather(H, 0 where invalid) + P_gt*pw + pb + E_gt*ew + eb  (fp32 out)
// Also writes the pure gathered H_exp as bf16 for the pitch/energy conv GEMMs.
__global__ void adapt_kernel(const float* __restrict__ H, const int* __restrict__ ridx,
                             const float* __restrict__ Pgt, const float* __restrict__ Egt,
                             const float* __restrict__ pw, const float* __restrict__ pb,
                             const float* __restrict__ ew, const float* __restrict__ eb,
                             float* __restrict__ out, unsigned short* __restrict__ hexpbf) {
    int i = blockIdx.x * 256 + threadIdx.x;   // B*T*C/4 = 4,194,304 float4s
    int f4 = i & 127;
    int p  = i >> 7;            // 0..32767 = b*T + t
    int b  = p >> 11;
    int r  = ridx[p];
    float pg = Pgt[p], eg = Egt[p];
    int f = f4 << 2;
    float4 pwv = *(const float4*)(pw + f);
    float4 pbv = *(const float4*)(pb + f);
    float4 ewv = *(const float4*)(ew + f);
    float4 ebv = *(const float4*)(eb + f);
    float4 h = make_float4(0.f, 0.f, 0.f, 0.f);
    if (r >= 0) h = *(const float4*)(H + ((long)b * S_ + r) * C_ + f);
    ushort4 hb;
    hb.x = f2bf(h.x); hb.y = f2bf(h.y); hb.z = f2bf(h.z); hb.w = f2bf(h.w);
    *(ushort4*)(hexpbf + (long)p * C_ + f) = hb;
    float4 o;
    o.x = h.x + pg * pwv.x + pbv.x + eg * ewv.x + ebv.x;
    o.y = h.y + pg * pwv.y + pbv.y + eg * ewv.y + ebv.y;
    o.z = h.z + pg * pwv.z + pbv.z + eg * ewv.z + ebv.z;
    o.w = h.w + pg * pwv.w + pbv.w + eg * ewv.w + ebv.w;
    *(float4*)(out + (long)p * C_ + f) = o;
}

// ---------------------------------------------------------------------------
// Conv-as-GEMM with bf16 MFMA (m97 structure: 128x128 tile, BK=32,
// global_load_lds width=16, unpadded [row][k] LDS layout).
//   D[f, p] = sum_{tap, c} W[tap][f][c] * X[(p + tap - 1)][c]
// (zero row when t+tap-1 out of [0,L)).  Positions p = b*L + t, row-contiguous.
// mode 0: dst(bf16)[p*C + f] = relu(D + bias[f])
// mode 1: atomicAdd(dst(f32)[p], sum_f relu(D + bias[f]) * wl[f])
__global__ __launch_bounds__(256, 2) void conv_mfma_kernel(
    const unsigned short* __restrict__ X,    // [B*L][C] bf16
    int Lshift,
    const unsigned short* __restrict__ wp,   // [3][F][C] bf16
    const float* __restrict__ bias,
    const float* __restrict__ wl,
    const unsigned short* __restrict__ zrow, // [C] bf16 zeros
    void* __restrict__ dstv,
    int mode)
{
    __shared__ unsigned short Wt[128 * 32];  // [f_row][k] 8 KB
    __shared__ unsigned short Xt[128 * 32];  // [p_row][k] 8 KB
    const int tid = threadIdx.x;
    const int n0 = blockIdx.x * 128;         // position tile
    const int m0 = blockIdx.y * 128;         // feature tile
    const int L = 1 << Lshift;

    floatx4 acc[4][4];
#pragma unroll
    for (int i = 0; i < 4; ++i)
#pragma unroll
        for (int j = 0; j < 4; ++j) acc[i][j] = (floatx4){0.f, 0.f, 0.f, 0.f};

    // staging: chunk c = row*4 + seg; thread handles chunks tid and tid+256
    const int row = tid >> 2, seg = tid & 3;
    const unsigned short* wsrc0 = wp + (long)(m0 + row) * C_ + seg * 8;
    const unsigned short* wsrc1 = wsrc0 + 64 * C_;
    const int p0 = n0 + row;
    const int p1 = p0 + 64;
    const int t0 = p0 & (L - 1);
    const int t1 = p1 & (L - 1);

    char* ldsW = (char*)Wt + (tid >> 6) * 1024;   // wave-uniform base
    char* ldsX = (char*)Xt + (tid >> 6) * 1024;

    // compute-side lane mapping (wave grid 2x2 over (m,n))
    const int lane = tid & 63;
    const int q = lane >> 4, lr = lane & 15;
    const int wm = (tid >> 6) & 1, wn = tid >> 7;
    const unsigned short* Wl = Wt + (wm * 64 + lr) * 32 + q * 8;
    const unsigned short* Xl = Xt + (wn * 64 + lr) * 32 + q * 8;

    for (int tap = 0; tap < 3; ++tap) {
        const unsigned short* wa = wsrc0 + (long)tap * (C_ * C_);
        const unsigned short* wb = wsrc1 + (long)tap * (C_ * C_);
        const int ts0 = t0 + tap - 1, ts1 = t1 + tap - 1;
        const unsigned short* xa = (ts0 >= 0 && ts0 < L)
            ? X + (long)(p0 + tap - 1) * C_ + seg * 8 : zrow + seg * 8;
        const unsigned short* xb = (ts1 >= 0 && ts1 < L)
            ? X + (long)(p1 + tap - 1) * C_ + seg * 8 : zrow + seg * 8;
        for (int c0 = 0; c0 < C_; c0 += 32) {
            __syncthreads();
            gld_lds16(ldsW,        wa + c0);
            gld_lds16(ldsW + 4096, wb + c0);
            gld_lds16(ldsX,        xa + c0);
            gld_lds16(ldsX + 4096, xb + c0);
            __syncthreads();
            short8 a[4], b[4];
#pragma unroll
            for (int i = 0; i < 4; ++i) {
                a[i] = *(const short8*)(Wl + i * 16 * 32);
                b[i] = *(const short8*)(Xl + i * 16 * 32);
            }
#pragma unroll
            for (int i = 0; i < 4; ++i)
#pragma unroll
                for (int j = 0; j < 4; ++j)
                    acc[i][j] = __builtin_amdgcn_mfma_f32_16x16x32_bf16(
                        a[i], b[j], acc[i][j], 0, 0, 0);
        }
    }

    // D lane mapping: col = lane&15 = p, row = q*4 + reg = f
    const int fbase = m0 + wm * 64 + q * 4;
    const int pbase = n0 + wn * 64 + lr;
    if (mode == 0) {
        unsigned short* dst = (unsigned short*)dstv;
#pragma unroll
        for (int i = 0; i < 4; ++i) {
            int f = fbase + i * 16;
            float4 bv = *(const float4*)(bias + f);
#pragma unroll
            for (int j = 0; j < 4; ++j) {
                int p = pbase + j * 16;
                ushort4 o;
                o.x = f2bf(fmaxf(acc[i][j][0] + bv.x, 0.f));
                o.y = f2bf(fmaxf(acc[i][j][1] + bv.y, 0.f));
                o.z = f2bf(fmaxf(acc[i][j][2] + bv.z, 0.f));
                o.w = f2bf(fmaxf(acc[i][j][3] + bv.w, 0.f));
                *(ushort4*)(dst + (long)p * C_ + f) = o;
            }
        }
    } else {
        float* dst = (float*)dstv;
#pragma unroll
        for (int j = 0; j < 4; ++j) {
            float s = 0.f;
#pragma unroll
            for (int i = 0; i < 4; ++i) {
                int f = fbase + i * 16;
                float4 bv = *(const float4*)(bias + f);
                float4 wv = *(const float4*)(wl + f);
                s += fmaxf(acc[i][j][0] + bv.x, 0.f) * wv.x;
                s += fmaxf(acc[i][j][1] + bv.y, 0.f) * wv.y;
                s += fmaxf(acc[i][j][2] + bv.z, 0.f) * wv.z;
                s += fmaxf(acc[i][j][3] + bv.w, 0.f) * wv.w;
            }
            s += __shfl_xor(s, 16, 64);
            s += __shfl_xor(s, 32, 64);
            if (lane < 16) atomicAdd(dst + pbase + j * 16, s);
        }
    }
}

// ---------------------------------------------------------------------------
extern "C" void kernel_launch(void* const* d_in, const int* in_sizes, int n_in,
                              void* d_out, int out_size, void* d_ws, size_t ws_size,
                              hipStream_t stream) {
    const float* H    = (const float*)d_in[0];
    const int*   Dgt  = (const int*)d_in[1];
    const float* Pgt  = (const float*)d_in[2];
    const float* Egt  = (const float*)d_in[3];
    const float* dp_w1 = (const float*)d_in[4];
    const float* dp_b1 = (const float*)d_in[5];
    const float* dp_w2 = (const float*)d_in[6];
    const float* dp_b2 = (const float*)d_in[7];
    const float* dp_wl = (const float*)d_in[8];
    const float* dp_bl = (const float*)d_in[9];
    const float* pp_w1 = (const float*)d_in[10];
    const float* pp_b1 = (const float*)d_in[11];
    const float* pp_w2 = (const float*)d_in[12];
    const float* pp_b2 = (const float*)d_in[13];
    const float* pp_wl = (const float*)d_in[14];
    const float* pp_bl = (const float*)d_in[15];
    const float* ep_w1 = (const float*)d_in[16];
    const float* ep_b1 = (const float*)d_in[17];
    const float* ep_w2 = (const float*)d_in[18];
    const float* ep_b2 = (const float*)d_in[19];
    const float* ep_wl = (const float*)d_in[20];
    const float* ep_bl = (const float*)d_in[21];
    const float* pitch_w  = (const float*)d_in[22];
    const float* pitch_b  = (const float*)d_in[23];
    const float* energy_w = (const float*)d_in[24];
    const float* energy_b = (const float*)d_in[25];

    float* out     = (float*)d_out;
    float* H_adapt = out;                       // 16*2048*512 = 16,777,216
    float* D_pred  = out + 16777216;            // 16*512 = 8192
    float* P_pred  = out + 16785408;            // 16*2048 = 32768
    float* E_pred  = out + 16818176;            // 16*2048 = 32768

    char* ws = (char*)d_ws;
    size_t off = 0;
    unsigned short* wpack = (unsigned short*)(ws + off); off += 6UL * 786432UL * 2UL;  // 9.4 MB
    unsigned short* Hbf   = (unsigned short*)(ws + off); off += 4194304UL * 2UL;       // 8 MB
    unsigned short* Hexpb = (unsigned short*)(ws + off); off += 16777216UL * 2UL;      // 33.5 MB
    unsigned short* h1bf  = (unsigned short*)(ws + off); off += 16777216UL * 2UL;      // 33.5 MB
    unsigned short* zrow  = (unsigned short*)(ws + off); off += 512UL * 2UL;
    off = (off + 255) & ~(size_t)255;
    int* ridx_exp = (int*)(ws + off); off += (size_t)B_ * T_ * 4;

    // Pack all six conv weights to bf16 (3,F,C)
    hipLaunchKernelGGL(pack_w_bf16_kernel, dim3(1024), dim3(256), 0, stream, dp_w1, wpack + 0UL * 786432);
    hipLaunchKernelGGL(pack_w_bf16_kernel, dim3(1024), dim3(256), 0, stream, dp_w2, wpack + 1UL * 786432);
    hipLaunchKernelGGL(pack_w_bf16_kernel, dim3(1024), dim3(256), 0, stream, pp_w1, wpack + 2UL * 786432);
    hipLaunchKernelGGL(pack_w_bf16_kernel, dim3(1024), dim3(256), 0, stream, pp_w2, wpack + 3UL * 786432);
    hipLaunchKernelGGL(pack_w_bf16_kernel, dim3(1024), dim3(256), 0, stream, ep_w1, wpack + 4UL * 786432);
    hipLaunchKernelGGL(pack_w_bf16_kernel, dim3(1024), dim3(256), 0, stream, ep_w2, wpack + 5UL * 786432);

    hipLaunchKernelGGL(cvt_bf16_kernel, dim3(4096), dim3(256), 0, stream, H, Hbf, 1048576);
    hipLaunchKernelGGL(zrow_kernel, dim3(2), dim3(256), 0, stream, zrow);
    hipLaunchKernelGGL(expand_rowidx_kernel, dim3(B_), dim3(S_), 0, stream, Dgt, ridx_exp);

    // H_adapted (fp32) + H_exp (bf16) in one pass
    hipLaunchKernelGGL(adapt_kernel, dim3(16384), dim3(256), 0, stream,
                       H, ridx_exp, Pgt, Egt, pitch_w, pitch_b, energy_w, energy_b,
                       H_adapt, Hexpb);

    // Init predictor outputs with final bias (atomic accumulation target)
    hipLaunchKernelGGL(fill_kernel, dim3(32), dim3(256), 0, stream, D_pred, 8192, dp_bl);
    hipLaunchKernelGGL(fill_kernel, dim3(128), dim3(256), 0, stream, P_pred, 32768, pp_bl);
    hipLaunchKernelGGL(fill_kernel, dim3(128), dim3(256), 0, stream, E_pred, 32768, ep_bl);

    // Duration predictor on H (L=512)
    hipLaunchKernelGGL(conv_mfma_kernel, dim3(64, 4), dim3(256), 0, stream,
                       Hbf, 9, wpack + 0UL * 786432, dp_b1, (const float*)nullptr, zrow, h1bf, 0);
    hipLaunchKernelGGL(conv_mfma_kernel, dim3(64, 4), dim3(256), 0, stream,
                       h1bf, 9, wpack + 1UL * 786432, dp_b2, dp_wl, zrow, D_pred, 1);

    // Pitch predictor on H_exp (L=2048)
    hipLaunchKernelGGL(conv_mfma_kernel, dim3(256, 4), dim3(256), 0, stream,
                       Hexpb, 11, wpack + 2UL * 786432, pp_b1, (const float*)nullptr, zrow, h1bf, 0);
    hipLaunchKernelGGL(conv_mfma_kernel, dim3(256, 4), dim3(256), 0, stream,
                       h1bf, 11, wpack + 3UL * 786432, pp_b2, pp_wl, zrow, P_pred, 1);

    // Energy predictor on H_exp
    hipLaunchKernelGGL(conv_mfma_kernel, dim3(256, 4), dim3(256), 0, stream,
                       Hexpb, 11, wpack + 4UL * 786432, ep_b1, (const float*)nullptr, zrow, h1bf, 0);
    hipLaunchKernelGGL(conv_mfma_kernel, dim3(256, 4), dim3(256), 0, stream,
                       h1bf, 11, wpack + 5UL * 786432, ep_b2, ep_wl, zrow, E_pred, 1);
}

// Round 3
// 412.670 us; speedup vs baseline: 7.7749x; 1.1648x over previous
//
#include <hip/hip_runtime.h>

// VarianceAdaptor: B=16, S=512, C(D_MODEL)=F(FILTER)=512, K=3, T(MAX_FRAMES)=2048
#define B_ 16
#define S_ 512
#define C_ 512
#define T_ 2048

typedef __attribute__((ext_vector_type(8))) short short8;
typedef __attribute__((ext_vector_type(4))) float floatx4;

__device__ __forceinline__ unsigned short f2bf(float x) {
    union { float f; unsigned u; } c; c.f = x;
    unsigned r = (c.u + 0x7fffu + ((c.u >> 16) & 1u)) >> 16;
    return (unsigned short)r;
}

// async global->LDS, 16B per lane; lds dest = wave-uniform base + lane*16
__device__ __forceinline__ void gld_lds16(void* l, const void* g) {
    __builtin_amdgcn_global_load_lds(
        (const __attribute__((address_space(1))) void*)g,
        (__attribute__((address_space(3))) void*)l, 16, 0, 0);
}

// ---------------------------------------------------------------------------
// Fused prep: pack 6 conv weights (F,C,3)fp32 -> (3,F,C)bf16, cast H->bf16,
// zero the zrow. One launch instead of 8.
__global__ void prep_kernel(const float* __restrict__ w0, const float* __restrict__ w1,
                            const float* __restrict__ w2, const float* __restrict__ w3,
                            const float* __restrict__ w4, const float* __restrict__ w5,
                            unsigned short* __restrict__ wpack,
                            const float* __restrict__ H, unsigned short* __restrict__ Hbf,
                            unsigned short* __restrict__ zrow) {
    int blk = blockIdx.x;
    if (blk < 6144) {                      // weight pack: 6 x 1024 blocks
        int which = blk >> 10;
        const float* w = which == 0 ? w0 : which == 1 ? w1 : which == 2 ? w2
                       : which == 3 ? w3 : which == 4 ? w4 : w5;
        unsigned short* wp = wpack + (long)which * 786432;
        int i = (blk & 1023) * 256 + threadIdx.x;   // i over F*C = 262144
        const float* s = w + (long)i * 3;
        wp[i]          = f2bf(s[0]);
        wp[i + 262144] = f2bf(s[1]);
        wp[i + 524288] = f2bf(s[2]);
    } else if (blk < 10240) {              // H fp32 -> bf16: 4096 blocks x 4 elems
        int i = (blk - 6144) * 256 + threadIdx.x;
        float4 v = *(const float4*)(H + (long)i * 4);
        ushort4 o;
        o.x = f2bf(v.x); o.y = f2bf(v.y); o.z = f2bf(v.z); o.w = f2bf(v.w);
        *(ushort4*)(Hbf + (long)i * 4) = o;
    } else {                               // zrow: 2 blocks
        zrow[(blk - 10240) * 256 + threadIdx.x] = 0;
    }
}

// Per batch: cumsum(clamp(D,0)) over S, then rowidx[t] = searchsorted_right(csum,t)
// clamped to S-1, or -1 where t >= min(total, T).
__global__ void expand_rowidx_kernel(const int* __restrict__ Dgt, int* __restrict__ ridx) {
    __shared__ int cs[S_];
    int b = blockIdx.x, s = threadIdx.x;
    int d = Dgt[b * S_ + s];
    cs[s] = d < 0 ? 0 : d;
    __syncthreads();
    for (int off = 1; off < S_; off <<= 1) {
        int v = (s >= off) ? cs[s - off] : 0;
        __syncthreads();
        cs[s] += v;
        __syncthreads();
    }
    int total = cs[S_ - 1];
    int limit = total < T_ ? total : T_;
    for (int t = s; t < T_; t += S_) {
        int lo = 0, hi = S_;
        while (lo < hi) { int mid = (lo + hi) >> 1; if (cs[mid] <= t) lo = mid + 1; else hi = mid; }
        if (lo > S_ - 1) lo = S_ - 1;
        ridx[b * T_ + t] = (t < limit) ? lo : -1;
    }
}

// Init all three predictor outputs with their final bias (atomic targets). 288 blocks.
__global__ void fill3_kernel(float* __restrict__ D, float* __restrict__ P, float* __restrict__ E,
                             const float* __restrict__ dbl, const float* __restrict__ pbl,
                             const float* __restrict__ ebl) {
    int i = blockIdx.x * 256 + threadIdx.x;
    if (i < 8192) D[i] = dbl[0];
    else if (i < 40960) P[i - 8192] = pbl[0];
    else E[i - 40960] = ebl[0];
}

// H_adapted = gather(H, 0 where invalid) + P_gt*pw + pb + E_gt*ew + eb  (fp32 out)
__global__ void adapt_kernel(const float* __restrict__ H, const int* __restrict__ ridx,
                             const float* __restrict__ Pgt, const float* __restrict__ Egt,
                             const float* __restrict__ pw, const float* __restrict__ pb,
                             const float* __restrict__ ew, const float* __restrict__ eb,
                             float* __restrict__ out) {
    int i = blockIdx.x * 256 + threadIdx.x;   // B*T*C/4 = 4,194,304 float4s
    int f4 = i & 127;
    int p  = i >> 7;            // 0..32767 = b*T + t
    int b  = p >> 11;
    int r  = ridx[p];
    float pg = Pgt[p], eg = Egt[p];
    int f = f4 << 2;
    float4 pwv = *(const float4*)(pw + f);
    float4 pbv = *(const float4*)(pb + f);
    float4 ewv = *(const float4*)(ew + f);
    float4 ebv = *(const float4*)(eb + f);
    float4 h = make_float4(0.f, 0.f, 0.f, 0.f);
    if (r >= 0) h = *(const float4*)(H + ((long)b * S_ + r) * C_ + f);
    float4 o;
    o.x = h.x + pg * pwv.x + pbv.x + eg * ewv.x + ebv.x;
    o.y = h.y + pg * pwv.y + pbv.y + eg * ewv.y + ebv.y;
    o.z = h.z + pg * pwv.z + pbv.z + eg * ewv.z + ebv.z;
    o.w = h.w + pg * pwv.w + pbv.w + eg * ewv.w + ebv.w;
    *(float4*)(out + (long)p * C_ + f) = o;
}

// ---------------------------------------------------------------------------
// Tap-fused conv-as-GEMM, bf16 MFMA.  Per c-chunk (K=32): stage W for all 3
// taps (3x128x32) + one X position tile of 130 rows (n0-1 .. n0+128); all 3
// taps' MFMAs read the same X tile at a row offset. 48 MFMA per barrier-pair
// (vs 16 in the m97 per-tap loop); X staging traffic /3.
//   D[f, p] = sum_{tap, c} W[tap][f][c] * X[row(p + tap - 1)][c]
// Rows resolved through optional ridx (length-regulator gather) at staging.
// mode 0: dst(bf16)[p*C + f] = relu(D + bias[f])
// mode 1: atomicAdd(dst(f32)[p], sum_f relu(D + bias[f]) * wl[f])
struct ConvJob {
    const unsigned short* X;    // bf16 rows [B << Bshift][C]
    const int* ridx;            // per (b,t) row-in-batch, or nullptr = identity
    int Lshift;                 // log2 positions per batch
    int Bshift;                 // log2 rows per batch of X
    const unsigned short* wp;   // [3][512][512] bf16
    const float* bias;
    const float* wl;
    void* dst;
    int nx;                     // active position tiles
};

__global__ __launch_bounds__(256, 4) void conv_mfma_kernel(
    ConvJob j0, ConvJob j1, const unsigned short* __restrict__ zrow, int mode)
{
    __shared__ unsigned short Wt[3 * 128 * 32];  // 24 KB  [tap][frow][k32]
    __shared__ unsigned short Xt[136 * 32];      // 8.5 KB [posrow][k32], row0 = n0-1
    const ConvJob j = (blockIdx.y < 4) ? j0 : j1;
    if ((int)blockIdx.x >= j.nx) return;
    const int tid = threadIdx.x;
    const int m0 = (blockIdx.y & 3) * 128;
    const int n0 = blockIdx.x * 128;
    const int L = 1 << j.Lshift;
    const int b = n0 >> j.Lshift;
    const int t0 = n0 & (L - 1);

    floatx4 acc[4][4];
#pragma unroll
    for (int i = 0; i < 4; ++i)
#pragma unroll
        for (int jj = 0; jj < 4; ++jj) acc[i][jj] = (floatx4){0.f, 0.f, 0.f, 0.f};

    // --- staging pointers (chunk idx -> 16B) ---
    // W: 1536 chunks, idx = tid + q*256; tap=idx>>9, row=(idx&511)>>2, seg=idx&3
    const unsigned short* wptr[6];
#pragma unroll
    for (int q = 0; q < 6; ++q) {
        int idx = tid + q * 256;
        int tap = idx >> 9, rem = idx & 511;
        wptr[q] = j.wp + (long)tap * (C_ * C_) + (long)(m0 + (rem >> 2)) * C_ + (rem & 3) * 8;
    }
    // X: 520 chunks over rows rho=0..129 (position n0-1+rho), 4 segs each
    auto xrow = [&](int rho) -> const unsigned short* {
        int t = t0 - 1 + rho;
        if (t < 0 || t >= L) return zrow;
        int r = j.ridx ? j.ridx[(b << j.Lshift) + t] : t;
        if (r < 0) return zrow;
        return j.X + ((long)(b << j.Bshift) + r) * C_;
    };
    const unsigned short* xptr0 = xrow(tid >> 2) + (tid & 3) * 8;
    const unsigned short* xptr1 = xrow(64 + (tid >> 2)) + (tid & 3) * 8;
    const unsigned short* xptr2 = (tid < 8) ? (xrow(128 + (tid >> 2)) + (tid & 3) * 8) : zrow;

    char* wbase = (char*)Wt + (tid >> 6) * 1024;   // wave-uniform LDS bases
    char* xbase = (char*)Xt + (tid >> 6) * 1024;

    // --- compute-side lane mapping (wave grid 2(m) x 2(n)) ---
    const int lane = tid & 63;
    const int q8 = (lane >> 4) * 8, lr = lane & 15;
    const int wm = (tid >> 6) & 1, wn = tid >> 7;

    for (int c0 = 0; c0 < C_; c0 += 32) {
        __syncthreads();
#pragma unroll
        for (int q = 0; q < 6; ++q)
            gld_lds16(wbase + q * 4096, wptr[q] + c0);
        gld_lds16(xbase, xptr0 + c0);
        gld_lds16(xbase + 4096, xptr1 + c0);
        if (tid < 8)
            gld_lds16((char*)Xt + 8192, xptr2 + c0);
        __syncthreads();
#pragma unroll
        for (int tap = 0; tap < 3; ++tap) {
            const unsigned short* Wl = Wt + ((tap * 128) + wm * 64 + lr) * 32 + q8;
            const unsigned short* Xl = Xt + (wn * 64 + lr + tap) * 32 + q8;
            short8 a[4], bf[4];
#pragma unroll
            for (int i = 0; i < 4; ++i) {
                a[i]  = *(const short8*)(Wl + i * 16 * 32);
                bf[i] = *(const short8*)(Xl + i * 16 * 32);
            }
#pragma unroll
            for (int i = 0; i < 4; ++i)
#pragma unroll
                for (int jj = 0; jj < 4; ++jj)
                    acc[i][jj] = __builtin_amdgcn_mfma_f32_16x16x32_bf16(
                        a[i], bf[jj], acc[i][jj], 0, 0, 0);
        }
    }

    // D lane mapping: col = lane&15 = p, row = q*4 + reg = f
    const int fbase = m0 + wm * 64 + (q8 >> 1);    // q*4
    const int pbase = n0 + wn * 64 + lr;
    if (mode == 0) {
        unsigned short* dst = (unsigned short*)j.dst;
#pragma unroll
        for (int i = 0; i < 4; ++i) {
            int f = fbase + i * 16;
            float4 bv = *(const float4*)(j.bias + f);
#pragma unroll
            for (int jj = 0; jj < 4; ++jj) {
                int p = pbase + jj * 16;
                ushort4 o;
                o.x = f2bf(fmaxf(acc[i][jj][0] + bv.x, 0.f));
                o.y = f2bf(fmaxf(acc[i][jj][1] + bv.y, 0.f));
                o.z = f2bf(fmaxf(acc[i][jj][2] + bv.z, 0.f));
                o.w = f2bf(fmaxf(acc[i][jj][3] + bv.w, 0.f));
                *(ushort4*)(dst + (long)p * C_ + f) = o;
            }
        }
    } else {
        float* dst = (float*)j.dst;
#pragma unroll
        for (int jj = 0; jj < 4; ++jj) {
            float s = 0.f;
#pragma unroll
            for (int i = 0; i < 4; ++i) {
                int f = fbase + i * 16;
                float4 bv = *(const float4*)(j.bias + f);
                float4 wv = *(const float4*)(j.wl + f);
                s += fmaxf(acc[i][jj][0] + bv.x, 0.f) * wv.x;
                s += fmaxf(acc[i][jj][1] + bv.y, 0.f) * wv.y;
                s += fmaxf(acc[i][jj][2] + bv.z, 0.f) * wv.z;
                s += fmaxf(acc[i][jj][3] + bv.w, 0.f) * wv.w;
            }
            s += __shfl_xor(s, 16, 64);
            s += __shfl_xor(s, 32, 64);
            if (lane < 16) atomicAdd(dst + pbase + jj * 16, s);
        }
    }
}

// ---------------------------------------------------------------------------
extern "C" void kernel_launch(void* const* d_in, const int* in_sizes, int n_in,
                              void* d_out, int out_size, void* d_ws, size_t ws_size,
                              hipStream_t stream) {
    const float* H    = (const float*)d_in[0];
    const int*   Dgt  = (const int*)d_in[1];
    const float* Pgt  = (const float*)d_in[2];
    const float* Egt  = (const float*)d_in[3];
    const float* dp_w1 = (const float*)d_in[4];
    const float* dp_b1 = (const float*)d_in[5];
    const float* dp_w2 = (const float*)d_in[6];
    const float* dp_b2 = (const float*)d_in[7];
    const float* dp_wl = (const float*)d_in[8];
    const float* dp_bl = (const float*)d_in[9];
    const float* pp_w1 = (const float*)d_in[10];
    const float* pp_b1 = (const float*)d_in[11];
    const float* pp_w2 = (const float*)d_in[12];
    const float* pp_b2 = (const float*)d_in[13];
    const float* pp_wl = (const float*)d_in[14];
    const float* pp_bl = (const float*)d_in[15];
    const float* ep_w1 = (const float*)d_in[16];
    const float* ep_b1 = (const float*)d_in[17];
    const float* ep_w2 = (const float*)d_in[18];
    const float* ep_b2 = (const float*)d_in[19];
    const float* ep_wl = (const float*)d_in[20];
    const float* ep_bl = (const float*)d_in[21];
    const float* pitch_w  = (const float*)d_in[22];
    const float* pitch_b  = (const float*)d_in[23];
    const float* energy_w = (const float*)d_in[24];
    const float* energy_b = (const float*)d_in[25];

    float* out     = (float*)d_out;
    float* H_adapt = out;                       // 16*2048*512 = 16,777,216
    float* D_pred  = out + 16777216;            // 16*512 = 8192
    float* P_pred  = out + 16785408;            // 16*2048 = 32768
    float* E_pred  = out + 16818176;            // 16*2048 = 32768

    char* ws = (char*)d_ws;
    size_t off = 0;
    unsigned short* wpack = (unsigned short*)(ws + off); off += 6UL * 786432UL * 2UL;  // 9.4 MB
    unsigned short* Hbf   = (unsigned short*)(ws + off); off += 4194304UL * 2UL;       // 8 MB
    unsigned short* h1a   = (unsigned short*)(ws + off); off += 16777216UL * 2UL;      // 33.5 MB (pp, then ep)
    unsigned short* h1dp  = (unsigned short*)(ws + off); off += 4194304UL * 2UL;       // 8 MB
    unsigned short* zrow  = (unsigned short*)(ws + off); off += 512UL * 2UL;
    off = (off + 255) & ~(size_t)255;
    int* ridx_exp = (int*)(ws + off); off += (size_t)B_ * T_ * 4;
    // total ~60 MB

    hipLaunchKernelGGL(prep_kernel, dim3(10242), dim3(256), 0, stream,
                       dp_w1, dp_w2, pp_w1, pp_w2, ep_w1, ep_w2, wpack, H, Hbf, zrow);
    hipLaunchKernelGGL(expand_rowidx_kernel, dim3(B_), dim3(S_), 0, stream, Dgt, ridx_exp);
    hipLaunchKernelGGL(adapt_kernel, dim3(16384), dim3(256), 0, stream,
                       H, ridx_exp, Pgt, Egt, pitch_w, pitch_b, energy_w, energy_b, H_adapt);
    hipLaunchKernelGGL(fill3_kernel, dim3(288), dim3(256), 0, stream,
                       D_pred, P_pred, E_pred, dp_bl, pp_bl, ep_bl);

    ConvJob j_pp1 = { Hbf, ridx_exp, 11, 9, wpack + 2UL * 786432, pp_b1, nullptr, h1a,  256 };
    ConvJob j_dp1 = { Hbf, nullptr,   9, 9, wpack + 0UL * 786432, dp_b1, nullptr, h1dp,  64 };
    ConvJob j_pp2 = { h1a, nullptr,  11, 11, wpack + 3UL * 786432, pp_b2, pp_wl, P_pred, 256 };
    ConvJob j_dp2 = { h1dp, nullptr,  9,  9, wpack + 1UL * 786432, dp_b2, dp_wl, D_pred,  64 };
    ConvJob j_ep1 = { Hbf, ridx_exp, 11, 9, wpack + 4UL * 786432, ep_b1, nullptr, h1a,  256 };
    ConvJob j_ep2 = { h1a, nullptr,  11, 11, wpack + 5UL * 786432, ep_b2, ep_wl, E_pred, 256 };

    // pp + dp pipelines fused per stage; ep reuses h1a after pp's conv2 is done
    hipLaunchKernelGGL(conv_mfma_kernel, dim3(256, 8), dim3(256), 0, stream, j_pp1, j_dp1, zrow, 0);
    hipLaunchKernelGGL(conv_mfma_kernel, dim3(256, 8), dim3(256), 0, stream, j_pp2, j_dp2, zrow, 1);
    hipLaunchKernelGGL(conv_mfma_kernel, dim3(256, 4), dim3(256), 0, stream, j_ep1, j_ep1, zrow, 0);
    hipLaunchKernelGGL(conv_mfma_kernel, dim3(256, 4), dim3(256), 0, stream, j_ep2, j_ep2, zrow, 1);
}

// Round 4
// 387.878 us; speedup vs baseline: 8.2719x; 1.0639x over previous
//
#include <hip/hip_runtime.h>

// VarianceAdaptor: B=16, S=512, C(D_MODEL)=F(FILTER)=512, K=3, T(MAX_FRAMES)=2048
#define B_ 16
#define S_ 512
#define C_ 512
#define T_ 2048

typedef __attribute__((ext_vector_type(8))) short short8;
typedef __attribute__((ext_vector_type(4))) float floatx4;

__device__ __forceinline__ unsigned short f2bf(float x) {
    union { float f; unsigned u; } c; c.f = x;
    unsigned r = (c.u + 0x7fffu + ((c.u >> 16) & 1u)) >> 16;
    return (unsigned short)r;
}

// async global->LDS, 16B per lane; lds dest = wave-uniform base + lane*16
__device__ __forceinline__ void gld_lds16(void* l, const void* g) {
    __builtin_amdgcn_global_load_lds(
        (const __attribute__((address_space(1))) void*)g,
        (__attribute__((address_space(3))) void*)l, 16, 0, 0);
}

// ---------------------------------------------------------------------------
// Fused prep: pack 6 conv weights (F,C,3)fp32 -> (3,F,C)bf16, cast H->bf16,
// zero the zrow. One launch instead of 8.
__global__ void prep_kernel(const float* __restrict__ w0, const float* __restrict__ w1,
                            const float* __restrict__ w2, const float* __restrict__ w3,
                            const float* __restrict__ w4, const float* __restrict__ w5,
                            unsigned short* __restrict__ wpack,
                            const float* __restrict__ H, unsigned short* __restrict__ Hbf,
                            unsigned short* __restrict__ zrow) {
    int blk = blockIdx.x;
    if (blk < 6144) {                      // weight pack: 6 x 1024 blocks
        int which = blk >> 10;
        const float* w = which == 0 ? w0 : which == 1 ? w1 : which == 2 ? w2
                       : which == 3 ? w3 : which == 4 ? w4 : w5;
        unsigned short* wp = wpack + (long)which * 786432;
        int i = (blk & 1023) * 256 + threadIdx.x;   // i over F*C = 262144
        const float* s = w + (long)i * 3;
        wp[i]          = f2bf(s[0]);
        wp[i + 262144] = f2bf(s[1]);
        wp[i + 524288] = f2bf(s[2]);
    } else if (blk < 10240) {              // H fp32 -> bf16: 4096 blocks x 4 elems
        int i = (blk - 6144) * 256 + threadIdx.x;
        float4 v = *(const float4*)(H + (long)i * 4);
        ushort4 o;
        o.x = f2bf(v.x); o.y = f2bf(v.y); o.z = f2bf(v.z); o.w = f2bf(v.w);
        *(ushort4*)(Hbf + (long)i * 4) = o;
    } else {                               // zrow: 2 blocks
        zrow[(blk - 10240) * 256 + threadIdx.x] = 0;
    }
}

// Per batch: cumsum(clamp(D,0)) over S, then rowidx[t] = searchsorted_right(csum,t)
// clamped to S-1, or -1 where t >= min(total, T).
__global__ void expand_rowidx_kernel(const int* __restrict__ Dgt, int* __restrict__ ridx) {
    __shared__ int cs[S_];
    int b = blockIdx.x, s = threadIdx.x;
    int d = Dgt[b * S_ + s];
    cs[s] = d < 0 ? 0 : d;
    __syncthreads();
    for (int off = 1; off < S_; off <<= 1) {
        int v = (s >= off) ? cs[s - off] : 0;
        __syncthreads();
        cs[s] += v;
        __syncthreads();
    }
    int total = cs[S_ - 1];
    int limit = total < T_ ? total : T_;
    for (int t = s; t < T_; t += S_) {
        int lo = 0, hi = S_;
        while (lo < hi) { int mid = (lo + hi) >> 1; if (cs[mid] <= t) lo = mid + 1; else hi = mid; }
        if (lo > S_ - 1) lo = S_ - 1;
        ridx[b * T_ + t] = (t < limit) ? lo : -1;
    }
}

// Init all three predictor outputs with their final bias (atomic targets). 288 blocks.
__global__ void fill3_kernel(float* __restrict__ D, float* __restrict__ P, float* __restrict__ E,
                             const float* __restrict__ dbl, const float* __restrict__ pbl,
                             const float* __restrict__ ebl) {
    int i = blockIdx.x * 256 + threadIdx.x;
    if (i < 8192) D[i] = dbl[0];
    else if (i < 40960) P[i - 8192] = pbl[0];
    else E[i - 40960] = ebl[0];
}

// H_adapted = gather(H, 0 where invalid) + P_gt*pw + pb + E_gt*ew + eb  (fp32 out)
__global__ void adapt_kernel(const float* __restrict__ H, const int* __restrict__ ridx,
                             const float* __restrict__ Pgt, const float* __restrict__ Egt,
                             const float* __restrict__ pw, const float* __restrict__ pb,
                             const float* __restrict__ ew, const float* __restrict__ eb,
                             float* __restrict__ out) {
    int i = blockIdx.x * 256 + threadIdx.x;   // B*T*C/4 = 4,194,304 float4s
    int f4 = i & 127;
    int p  = i >> 7;            // 0..32767 = b*T + t
    int b  = p >> 11;
    int r  = ridx[p];
    float pg = Pgt[p], eg = Egt[p];
    int f = f4 << 2;
    float4 pwv = *(const float4*)(pw + f);
    float4 pbv = *(const float4*)(pb + f);
    float4 ewv = *(const float4*)(ew + f);
    float4 ebv = *(const float4*)(eb + f);
    float4 h = make_float4(0.f, 0.f, 0.f, 0.f);
    if (r >= 0) h = *(const float4*)(H + ((long)b * S_ + r) * C_ + f);
    float4 o;
    o.x = h.x + pg * pwv.x + pbv.x + eg * ewv.x + ebv.x;
    o.y = h.y + pg * pwv.y + pbv.y + eg * ewv.y + ebv.y;
    o.z = h.z + pg * pwv.z + pbv.z + eg * ewv.z + ebv.z;
    o.w = h.w + pg * pwv.w + pbv.w + eg * ewv.w + ebv.w;
    *(float4*)(out + (long)p * C_ + f) = o;
}

// ---------------------------------------------------------------------------
// Tap-fused conv-as-GEMM, bf16 MFMA, with XOR bank-conflict swizzle.
// LDS tiles are [row][32k] (64 B row stride). Naive fragment reads (16 rows x
// one 16 B column) are 8-way bank-conflicted. Fix: row r's four 16 B segments
// are stored permuted, position s holds logical segment s ^ ((r>>1)&3).
// global_load_lds keeps its contiguous lane->dest mapping; only the per-lane
// SOURCE address is permuted. Readers use position q ^ ((r>>1)&3), which
// reduces to a per-lane constant (row multiples of 8 vanish mod 4).
//   D[f, p] = sum_{tap, c} W[tap][f][c] * X[row(p + tap - 1)][c]
// mode 0: dst(bf16)[p*C + f] = relu(D + bias[f])
// mode 1: atomicAdd(dst(f32)[p], sum_f relu(D + bias[f]) * wl[f])
struct ConvJob {
    const unsigned short* X;    // bf16 rows [B << Bshift][C]
    const int* ridx;            // per (b,t) row-in-batch, or nullptr = identity
    int Lshift;                 // log2 positions per batch
    int Bshift;                 // log2 rows per batch of X
    const unsigned short* wp;   // [3][512][512] bf16
    const float* bias;
    const float* wl;
    void* dst;
    int nx;                     // active position tiles
};

__global__ __launch_bounds__(256, 4) void conv_mfma_kernel(
    ConvJob j0, ConvJob j1, const unsigned short* __restrict__ zrow, int mode)
{
    __shared__ unsigned short Wt[3 * 128 * 32];  // 24 KB  [tap][frow][k32]
    __shared__ unsigned short Xt[136 * 32];      // 8.5 KB [posrow][k32], row0 = n0-1
    const ConvJob j = (blockIdx.y < 4) ? j0 : j1;
    if ((int)blockIdx.x >= j.nx) return;
    const int tid = threadIdx.x;
    const int m0 = (blockIdx.y & 3) * 128;
    const int n0 = blockIdx.x * 128;
    const int L = 1 << j.Lshift;
    const int b = n0 >> j.Lshift;
    const int t0 = n0 & (L - 1);

    floatx4 acc[4][4];
#pragma unroll
    for (int i = 0; i < 4; ++i)
#pragma unroll
        for (int jj = 0; jj < 4; ++jj) acc[i][jj] = (floatx4){0.f, 0.f, 0.f, 0.f};

    // --- staging pointers (chunk idx -> 16B), source-seg XOR swizzle ---
    // W: 1536 chunks, idx = tid + q*256; tap=idx>>9, row=(idx&511)>>2, seg=idx&3
    const unsigned short* wptr[6];
#pragma unroll
    for (int q = 0; q < 6; ++q) {
        int idx = tid + q * 256;
        int tap = idx >> 9, rem = idx & 511;
        int row = rem >> 2;
        int sw = (rem & 3) ^ ((row >> 1) & 3);
        wptr[q] = j.wp + (long)tap * (C_ * C_) + (long)(m0 + row) * C_ + sw * 8;
    }
    // X: 520 chunks over rows rho=0..129 (position n0-1+rho), 4 segs each
    auto xrow = [&](int rho) -> const unsigned short* {
        int t = t0 - 1 + rho;
        if (t < 0 || t >= L) return zrow;
        int r = j.ridx ? j.ridx[(b << j.Lshift) + t] : t;
        if (r < 0) return zrow;
        return j.X + ((long)(b << j.Bshift) + r) * C_;
    };
    const int xs = tid & 3;
    const int rho0 = tid >> 2, rho1 = 64 + (tid >> 2), rho2 = 128 + (tid >> 2);
    const unsigned short* xptr0 = xrow(rho0) + (xs ^ ((rho0 >> 1) & 3)) * 8;
    const unsigned short* xptr1 = xrow(rho1) + (xs ^ ((rho1 >> 1) & 3)) * 8;
    const unsigned short* xptr2 = (tid < 8) ? (xrow(rho2) + (xs ^ ((rho2 >> 1) & 3)) * 8) : zrow;

    char* wbase = (char*)Wt + (tid >> 6) * 1024;   // wave-uniform LDS bases
    char* xbase = (char*)Xt + (tid >> 6) * 1024;

    // --- compute-side lane mapping (wave grid 2(m) x 2(n)) ---
    const int lane = tid & 63;
    const int q = lane >> 4, lr = lane & 15;
    const int wm = (tid >> 6) & 1, wn = tid >> 7;
    // swizzled per-lane k-quad byte offsets (constant across frags/chunks)
    const int qsW = (q ^ ((lr >> 1) & 3)) * 8;                    // W rows == lr (mod 8)
    int qsX[3];
#pragma unroll
    for (int tap = 0; tap < 3; ++tap)
        qsX[tap] = (q ^ (((lr + tap) >> 1) & 3)) * 8;             // X rows == lr+tap (mod 8)

    for (int c0 = 0; c0 < C_; c0 += 32) {
        __syncthreads();
#pragma unroll
        for (int qq = 0; qq < 6; ++qq)
            gld_lds16(wbase + qq * 4096, wptr[qq] + c0);
        gld_lds16(xbase, xptr0 + c0);
        gld_lds16(xbase + 4096, xptr1 + c0);
        if (tid < 8)
            gld_lds16((char*)Xt + 8192, xptr2 + c0);
        __syncthreads();
#pragma unroll
        for (int tap = 0; tap < 3; ++tap) {
            const unsigned short* Wl = Wt + ((tap * 128) + wm * 64 + lr) * 32 + qsW;
            const unsigned short* Xl = Xt + (wn * 64 + lr + tap) * 32 + qsX[tap];
            short8 a[4], bf[4];
#pragma unroll
            for (int i = 0; i < 4; ++i) {
                a[i]  = *(const short8*)(Wl + i * 16 * 32);
                bf[i] = *(const short8*)(Xl + i * 16 * 32);
            }
#pragma unroll
            for (int i = 0; i < 4; ++i)
#pragma unroll
                for (int jj = 0; jj < 4; ++jj)
                    acc[i][jj] = __builtin_amdgcn_mfma_f32_16x16x32_bf16(
                        a[i], bf[jj], acc[i][jj], 0, 0, 0);
        }
    }

    // D lane mapping: col = lane&15 = p, row = q*4 + reg = f
    const int fbase = m0 + wm * 64 + q * 4;
    const int pbase = n0 + wn * 64 + lr;
    if (mode == 0) {
        unsigned short* dst = (unsigned short*)j.dst;
#pragma unroll
        for (int i = 0; i < 4; ++i) {
            int f = fbase + i * 16;
            float4 bv = *(const float4*)(j.bias + f);
#pragma unroll
            for (int jj = 0; jj < 4; ++jj) {
                int p = pbase + jj * 16;
                ushort4 o;
                o.x = f2bf(fmaxf(acc[i][jj][0] + bv.x, 0.f));
                o.y = f2bf(fmaxf(acc[i][jj][1] + bv.y, 0.f));
                o.z = f2bf(fmaxf(acc[i][jj][2] + bv.z, 0.f));
                o.w = f2bf(fmaxf(acc[i][jj][3] + bv.w, 0.f));
                *(ushort4*)(dst + (long)p * C_ + f) = o;
            }
        }
    } else {
        float* dst = (float*)j.dst;
#pragma unroll
        for (int jj = 0; jj < 4; ++jj) {
            float s = 0.f;
#pragma unroll
            for (int i = 0; i < 4; ++i) {
                int f = fbase + i * 16;
                float4 bv = *(const float4*)(j.bias + f);
                float4 wv = *(const float4*)(j.wl + f);
                s += fmaxf(acc[i][jj][0] + bv.x, 0.f) * wv.x;
                s += fmaxf(acc[i][jj][1] + bv.y, 0.f) * wv.y;
                s += fmaxf(acc[i][jj][2] + bv.z, 0.f) * wv.z;
                s += fmaxf(acc[i][jj][3] + bv.w, 0.f) * wv.w;
            }
            s += __shfl_xor(s, 16, 64);
            s += __shfl_xor(s, 32, 64);
            if (lane < 16) atomicAdd(dst + pbase + jj * 16, s);
        }
    }
}

// ---------------------------------------------------------------------------
extern "C" void kernel_launch(void* const* d_in, const int* in_sizes, int n_in,
                              void* d_out, int out_size, void* d_ws, size_t ws_size,
                              hipStream_t stream) {
    const float* H    = (const float*)d_in[0];
    const int*   Dgt  = (const int*)d_in[1];
    const float* Pgt  = (const float*)d_in[2];
    const float* Egt  = (const float*)d_in[3];
    const float* dp_w1 = (const float*)d_in[4];
    const float* dp_b1 = (const float*)d_in[5];
    const float* dp_w2 = (const float*)d_in[6];
    const float* dp_b2 = (const float*)d_in[7];
    const float* dp_wl = (const float*)d_in[8];
    const float* dp_bl = (const float*)d_in[9];
    const float* pp_w1 = (const float*)d_in[10];
    const float* pp_b1 = (const float*)d_in[11];
    const float* pp_w2 = (const float*)d_in[12];
    const float* pp_b2 = (const float*)d_in[13];
    const float* pp_wl = (const float*)d_in[14];
    const float* pp_bl = (const float*)d_in[15];
    const float* ep_w1 = (const float*)d_in[16];
    const float* ep_b1 = (const float*)d_in[17];
    const float* ep_w2 = (const float*)d_in[18];
    const float* ep_b2 = (const float*)d_in[19];
    const float* ep_wl = (const float*)d_in[20];
    const float* ep_bl = (const float*)d_in[21];
    const float* pitch_w  = (const float*)d_in[22];
    const float* pitch_b  = (const float*)d_in[23];
    const float* energy_w = (const float*)d_in[24];
    const float* energy_b = (const float*)d_in[25];

    float* out     = (float*)d_out;
    float* H_adapt = out;                       // 16*2048*512 = 16,777,216
    float* D_pred  = out + 16777216;            // 16*512 = 8192
    float* P_pred  = out + 16785408;            // 16*2048 = 32768
    float* E_pred  = out + 16818176;            // 16*2048 = 32768

    char* ws = (char*)d_ws;
    size_t off = 0;
    unsigned short* wpack = (unsigned short*)(ws + off); off += 6UL * 786432UL * 2UL;  // 9.4 MB
    unsigned short* Hbf   = (unsigned short*)(ws + off); off += 4194304UL * 2UL;       // 8 MB
    unsigned short* h1a   = (unsigned short*)(ws + off); off += 16777216UL * 2UL;      // 33.5 MB (pp, then ep)
    unsigned short* h1dp  = (unsigned short*)(ws + off); off += 4194304UL * 2UL;       // 8 MB
    unsigned short* zrow  = (unsigned short*)(ws + off); off += 512UL * 2UL;
    off = (off + 255) & ~(size_t)255;
    int* ridx_exp = (int*)(ws + off); off += (size_t)B_ * T_ * 4;
    // total ~60 MB

    hipLaunchKernelGGL(prep_kernel, dim3(10242), dim3(256), 0, stream,
                       dp_w1, dp_w2, pp_w1, pp_w2, ep_w1, ep_w2, wpack, H, Hbf, zrow);
    hipLaunchKernelGGL(expand_rowidx_kernel, dim3(B_), dim3(S_), 0, stream, Dgt, ridx_exp);
    hipLaunchKernelGGL(adapt_kernel, dim3(16384), dim3(256), 0, stream,
                       H, ridx_exp, Pgt, Egt, pitch_w, pitch_b, energy_w, energy_b, H_adapt);
    hipLaunchKernelGGL(fill3_kernel, dim3(288), dim3(256), 0, stream,
                       D_pred, P_pred, E_pred, dp_bl, pp_bl, ep_bl);

    ConvJob j_pp1 = { Hbf, ridx_exp, 11, 9, wpack + 2UL * 786432, pp_b1, nullptr, h1a,  256 };
    ConvJob j_dp1 = { Hbf, nullptr,   9, 9, wpack + 0UL * 786432, dp_b1, nullptr, h1dp,  64 };
    ConvJob j_pp2 = { h1a, nullptr,  11, 11, wpack + 3UL * 786432, pp_b2, pp_wl, P_pred, 256 };
    ConvJob j_dp2 = { h1dp, nullptr,  9,  9, wpack + 1UL * 786432, dp_b2, dp_wl, D_pred,  64 };
    ConvJob j_ep1 = { Hbf, ridx_exp, 11, 9, wpack + 4UL * 786432, ep_b1, nullptr, h1a,  256 };
    ConvJob j_ep2 = { h1a, nullptr,  11, 11, wpack + 5UL * 786432, ep_b2, ep_wl, E_pred, 256 };

    // pp + dp pipelines fused per stage; ep reuses h1a after pp's conv2 is done
    hipLaunchKernelGGL(conv_mfma_kernel, dim3(256, 8), dim3(256), 0, stream, j_pp1, j_dp1, zrow, 0);
    hipLaunchKernelGGL(conv_mfma_kernel, dim3(256, 8), dim3(256), 0, stream, j_pp2, j_dp2, zrow, 1);
    hipLaunchKernelGGL(conv_mfma_kernel, dim3(256, 4), dim3(256), 0, stream, j_ep1, j_ep1, zrow, 0);
    hipLaunchKernelGGL(conv_mfma_kernel, dim3(256, 4), dim3(256), 0, stream, j_ep2, j_ep2, zrow, 1);
}

// Round 5
// 357.453 us; speedup vs baseline: 8.9760x; 1.0851x over previous
//
#include <hip/hip_runtime.h>

// VarianceAdaptor: B=16, S=512, C(D_MODEL)=F(FILTER)=512, K=3, T(MAX_FRAMES)=2048
#define B_ 16
#define S_ 512
#define C_ 512
#define T_ 2048

typedef __attribute__((ext_vector_type(8))) short short8;
typedef __attribute__((ext_vector_type(4))) float floatx4;

__device__ __forceinline__ unsigned short f2bf(float x) {
    union { float f; unsigned u; } c; c.f = x;
    unsigned r = (c.u + 0x7fffu + ((c.u >> 16) & 1u)) >> 16;
    return (unsigned short)r;
}

// async global->LDS, 16B per lane; lds dest = wave-uniform base + lane*16
__device__ __forceinline__ void gld_lds16(void* l, const void* g) {
    __builtin_amdgcn_global_load_lds(
        (const __attribute__((address_space(1))) void*)g,
        (__attribute__((address_space(3))) void*)l, 16, 0, 0);
}

// ---------------------------------------------------------------------------
// Fused prep: pack 6 conv weights (F,C,3)fp32 -> (3,F,C)bf16 [blocks 0..6143],
// cast H->bf16 [6144..10239], zero zrow [10240..10241], length-regulator
// rowidx [10242..10257], fill preds with final bias [10258..10545].
__global__ void prep_kernel(const float* __restrict__ w0, const float* __restrict__ w1,
                            const float* __restrict__ w2, const float* __restrict__ w3,
                            const float* __restrict__ w4, const float* __restrict__ w5,
                            unsigned short* __restrict__ wpack,
                            const float* __restrict__ H, unsigned short* __restrict__ Hbf,
                            unsigned short* __restrict__ zrow,
                            const int* __restrict__ Dgt, int* __restrict__ ridx,
                            float* __restrict__ Dp, float* __restrict__ Pp, float* __restrict__ Ep,
                            const float* __restrict__ dbl, const float* __restrict__ pbl,
                            const float* __restrict__ ebl) {
    __shared__ int cs[S_];
    __shared__ int ps[256];
    int blk = blockIdx.x;
    int tid = threadIdx.x;
    if (blk < 6144) {                      // weight pack: 6 x 1024 blocks
        int which = blk >> 10;
        const float* w = which == 0 ? w0 : which == 1 ? w1 : which == 2 ? w2
                       : which == 3 ? w3 : which == 4 ? w4 : w5;
        unsigned short* wp = wpack + (long)which * 786432;
        int i = (blk & 1023) * 256 + tid;   // i over F*C = 262144
        const float* s = w + (long)i * 3;
        wp[i]          = f2bf(s[0]);
        wp[i + 262144] = f2bf(s[1]);
        wp[i + 524288] = f2bf(s[2]);
    } else if (blk < 10240) {              // H fp32 -> bf16: 4096 blocks x 4 elems
        int i = (blk - 6144) * 256 + tid;
        float4 v = *(const float4*)(H + (long)i * 4);
        ushort4 o;
        o.x = f2bf(v.x); o.y = f2bf(v.y); o.z = f2bf(v.z); o.w = f2bf(v.w);
        *(ushort4*)(Hbf + (long)i * 4) = o;
    } else if (blk < 10242) {              // zrow: 2 blocks
        zrow[(blk - 10240) * 256 + tid] = 0;
    } else if (blk < 10258) {              // expand rowidx: 16 blocks (one/batch)
        int b = blk - 10242;
        int t2 = tid * 2;
        int d0 = Dgt[b * S_ + t2], d1 = Dgt[b * S_ + t2 + 1];
        int a0 = d0 < 0 ? 0 : d0, a1 = d1 < 0 ? 0 : d1;
        ps[tid] = a0 + a1;
        __syncthreads();
        for (int off = 1; off < 256; off <<= 1) {
            int v = (tid >= off) ? ps[tid - off] : 0;
            __syncthreads();
            ps[tid] += v;
            __syncthreads();
        }
        int incl = ps[tid];
        cs[t2] = incl - a1;
        cs[t2 + 1] = incl;
        __syncthreads();
        int total = cs[S_ - 1];
        int limit = total < T_ ? total : T_;
        for (int t = tid; t < T_; t += 256) {
            int lo = 0, hi = S_;
            while (lo < hi) { int mid = (lo + hi) >> 1; if (cs[mid] <= t) lo = mid + 1; else hi = mid; }
            if (lo > S_ - 1) lo = S_ - 1;
            ridx[b * T_ + t] = (t < limit) ? lo : -1;
        }
    } else {                               // fill preds: 288 blocks
        int i = (blk - 10258) * 256 + tid;
        if (i < 8192) Dp[i] = dbl[0];
        else if (i < 40960) Pp[i - 8192] = pbl[0];
        else Ep[i - 40960] = ebl[0];
    }
}

// ---------------------------------------------------------------------------
// Mega kernel: up to three tap-fused bf16-MFMA conv-GEMM jobs (block ranges
// [0,e0), [e0,e1), [e1,e2)) plus optional adapt blocks [e2, grid). Conv body
// identical to R4 (XOR bank-swizzle, 0 conflicts, ~890 TF plateau).
//   D[f, p] = sum_{tap, c} W[tap][f][c] * X[row(p + tap - 1)][c]
// mode 0: dst(bf16)[p*C + f] = relu(D + bias[f])
// mode 1: atomicAdd(dst(f32)[p], sum_f relu(D + bias[f]) * wl[f])
// Adapt blocks: H_adapted = gather(H) + P_gt*pw + pb + E_gt*ew + eb (fp32).
struct ConvJob {
    const unsigned short* X;    // bf16 rows [B << Bshift][C]
    const int* ridx;            // per (b,t) row-in-batch, or nullptr = identity
    int Lshift;                 // log2 positions per batch
    int Bshift;                 // log2 rows per batch of X
    const unsigned short* wp;   // [3][512][512] bf16
    const float* bias;
    const float* wl;
    void* dst;
    int nxshift;                // log2 of x-tiles (position tiles)
};

__global__ __launch_bounds__(256, 4) void mega_kernel(
    ConvJob j0, ConvJob j1, ConvJob j2, int e0, int e1, int e2, int mode,
    const unsigned short* __restrict__ zrow,
    const float* __restrict__ H, const int* __restrict__ aridx,
    const float* __restrict__ Pgt, const float* __restrict__ Egt,
    const float* __restrict__ pw, const float* __restrict__ pb,
    const float* __restrict__ ew, const float* __restrict__ eb,
    float* __restrict__ aout)
{
    __shared__ unsigned short Wt[3 * 128 * 32];  // 24 KB  [tap][frow][k32]
    __shared__ unsigned short Xt[136 * 32];      // 8.5 KB [posrow][k32], row0 = n0-1
    const int bx = blockIdx.x;
    const int tid = threadIdx.x;

    if (bx >= e2) {
        // ---- adapt path: 2048 blocks x 8 float4/thread ----
        int ab = bx - e2;
#pragma unroll
        for (int it = 0; it < 8; ++it) {
            int i = ab * 256 + tid + it * 524288;
            int f4 = i & 127;
            int p  = i >> 7;
            int b  = p >> 11;
            int r  = aridx[p];
            float pg = Pgt[p], eg = Egt[p];
            int f = f4 << 2;
            float4 pwv = *(const float4*)(pw + f);
            float4 pbv = *(const float4*)(pb + f);
            float4 ewv = *(const float4*)(ew + f);
            float4 ebv = *(const float4*)(eb + f);
            float4 h = make_float4(0.f, 0.f, 0.f, 0.f);
            if (r >= 0) h = *(const float4*)(H + ((long)b * S_ + r) * C_ + f);
            float4 o;
            o.x = h.x + pg * pwv.x + pbv.x + eg * ewv.x + ebv.x;
            o.y = h.y + pg * pwv.y + pbv.y + eg * ewv.y + ebv.y;
            o.z = h.z + pg * pwv.z + pbv.z + eg * ewv.z + ebv.z;
            o.w = h.w + pg * pwv.w + pbv.w + eg * ewv.w + ebv.w;
            *(float4*)(aout + (long)p * C_ + f) = o;
        }
        return;
    }

    ConvJob j;
    int local;
    if (bx < e0)      { j = j0; local = bx; }
    else if (bx < e1) { j = j1; local = bx - e0; }
    else              { j = j2; local = bx - e1; }
    const int m0 = (local >> j.nxshift) * 128;
    const int n0 = (local & ((1 << j.nxshift) - 1)) * 128;
    const int L = 1 << j.Lshift;
    const int b = n0 >> j.Lshift;
    const int t0 = n0 & (L - 1);

    floatx4 acc[4][4];
#pragma unroll
    for (int i = 0; i < 4; ++i)
#pragma unroll
        for (int jj = 0; jj < 4; ++jj) acc[i][jj] = (floatx4){0.f, 0.f, 0.f, 0.f};

    // --- staging pointers (chunk idx -> 16B), source-seg XOR swizzle ---
    const unsigned short* wptr[6];
#pragma unroll
    for (int q = 0; q < 6; ++q) {
        int idx = tid + q * 256;
        int tap = idx >> 9, rem = idx & 511;
        int row = rem >> 2;
        int sw = (rem & 3) ^ ((row >> 1) & 3);
        wptr[q] = j.wp + (long)tap * (C_ * C_) + (long)(m0 + row) * C_ + sw * 8;
    }
    auto xrow = [&](int rho) -> const unsigned short* {
        int t = t0 - 1 + rho;
        if (t < 0 || t >= L) return zrow;
        int r = j.ridx ? j.ridx[(b << j.Lshift) + t] : t;
        if (r < 0) return zrow;
        return j.X + ((long)(b << j.Bshift) + r) * C_;
    };
    const int xs = tid & 3;
    const int rho0 = tid >> 2, rho1 = 64 + (tid >> 2), rho2 = 128 + (tid >> 2);
    const unsigned short* xptr0 = xrow(rho0) + (xs ^ ((rho0 >> 1) & 3)) * 8;
    const unsigned short* xptr1 = xrow(rho1) + (xs ^ ((rho1 >> 1) & 3)) * 8;
    const unsigned short* xptr2 = (tid < 8) ? (xrow(rho2) + (xs ^ ((rho2 >> 1) & 3)) * 8) : zrow;

    char* wbase = (char*)Wt + (tid >> 6) * 1024;   // wave-uniform LDS bases
    char* xbase = (char*)Xt + (tid >> 6) * 1024;

    // --- compute-side lane mapping (wave grid 2(m) x 2(n)) ---
    const int lane = tid & 63;
    const int q = lane >> 4, lr = lane & 15;
    const int wm = (tid >> 6) & 1, wn = tid >> 7;
    const int qsW = (q ^ ((lr >> 1) & 3)) * 8;
    int qsX[3];
#pragma unroll
    for (int tap = 0; tap < 3; ++tap)
        qsX[tap] = (q ^ (((lr + tap) >> 1) & 3)) * 8;

    for (int c0 = 0; c0 < C_; c0 += 32) {
        __syncthreads();
#pragma unroll
        for (int qq = 0; qq < 6; ++qq)
            gld_lds16(wbase + qq * 4096, wptr[qq] + c0);
        gld_lds16(xbase, xptr0 + c0);
        gld_lds16(xbase + 4096, xptr1 + c0);
        if (tid < 8)
            gld_lds16((char*)Xt + 8192, xptr2 + c0);
        __syncthreads();
#pragma unroll
        for (int tap = 0; tap < 3; ++tap) {
            const unsigned short* Wl = Wt + ((tap * 128) + wm * 64 + lr) * 32 + qsW;
            const unsigned short* Xl = Xt + (wn * 64 + lr + tap) * 32 + qsX[tap];
            short8 a[4], bf[4];
#pragma unroll
            for (int i = 0; i < 4; ++i) {
                a[i]  = *(const short8*)(Wl + i * 16 * 32);
                bf[i] = *(const short8*)(Xl + i * 16 * 32);
            }
#pragma unroll
            for (int i = 0; i < 4; ++i)
#pragma unroll
                for (int jj = 0; jj < 4; ++jj)
                    acc[i][jj] = __builtin_amdgcn_mfma_f32_16x16x32_bf16(
                        a[i], bf[jj], acc[i][jj], 0, 0, 0);
        }
    }

    // D lane mapping: col = lane&15 = p, row = q*4 + reg = f
    const int fbase = m0 + wm * 64 + q * 4;
    const int pbase = n0 + wn * 64 + lr;
    if (mode == 0) {
        unsigned short* dst = (unsigned short*)j.dst;
#pragma unroll
        for (int i = 0; i < 4; ++i) {
            int f = fbase + i * 16;
            float4 bv = *(const float4*)(j.bias + f);
#pragma unroll
            for (int jj = 0; jj < 4; ++jj) {
                int p = pbase + jj * 16;
                ushort4 o;
                o.x = f2bf(fmaxf(acc[i][jj][0] + bv.x, 0.f));
                o.y = f2bf(fmaxf(acc[i][jj][1] + bv.y, 0.f));
                o.z = f2bf(fmaxf(acc[i][jj][2] + bv.z, 0.f));
                o.w = f2bf(fmaxf(acc[i][jj][3] + bv.w, 0.f));
                *(ushort4*)(dst + (long)p * C_ + f) = o;
            }
        }
    } else {
        float* dst = (float*)j.dst;
#pragma unroll
        for (int jj = 0; jj < 4; ++jj) {
            float s = 0.f;
#pragma unroll
            for (int i = 0; i < 4; ++i) {
                int f = fbase + i * 16;
                float4 bv = *(const float4*)(j.bias + f);
                float4 wv = *(const float4*)(j.wl + f);
                s += fmaxf(acc[i][jj][0] + bv.x, 0.f) * wv.x;
                s += fmaxf(acc[i][jj][1] + bv.y, 0.f) * wv.y;
                s += fmaxf(acc[i][jj][2] + bv.z, 0.f) * wv.z;
                s += fmaxf(acc[i][jj][3] + bv.w, 0.f) * wv.w;
            }
            s += __shfl_xor(s, 16, 64);
            s += __shfl_xor(s, 32, 64);
            if (lane < 16) atomicAdd(dst + pbase + jj * 16, s);
        }
    }
}

// ---------------------------------------------------------------------------
extern "C" void kernel_launch(void* const* d_in, const int* in_sizes, int n_in,
                              void* d_out, int out_size, void* d_ws, size_t ws_size,
                              hipStream_t stream) {
    const float* H    = (const float*)d_in[0];
    const int*   Dgt  = (const int*)d_in[1];
    const float* Pgt  = (const float*)d_in[2];
    const float* Egt  = (const float*)d_in[3];
    const float* dp_w1 = (const float*)d_in[4];
    const float* dp_b1 = (const float*)d_in[5];
    const float* dp_w2 = (const float*)d_in[6];
    const float* dp_b2 = (const float*)d_in[7];
    const float* dp_wl = (const float*)d_in[8];
    const float* dp_bl = (const float*)d_in[9];
    const float* pp_w1 = (const float*)d_in[10];
    const float* pp_b1 = (const float*)d_in[11];
    const float* pp_w2 = (const float*)d_in[12];
    const float* pp_b2 = (const float*)d_in[13];
    const float* pp_wl = (const float*)d_in[14];
    const float* pp_bl = (const float*)d_in[15];
    const float* ep_w1 = (const float*)d_in[16];
    const float* ep_b1 = (const float*)d_in[17];
    const float* ep_w2 = (const float*)d_in[18];
    const float* ep_b2 = (const float*)d_in[19];
    const float* ep_wl = (const float*)d_in[20];
    const float* ep_bl = (const float*)d_in[21];
    const float* pitch_w  = (const float*)d_in[22];
    const float* pitch_b  = (const float*)d_in[23];
    const float* energy_w = (const float*)d_in[24];
    const float* energy_b = (const float*)d_in[25];

    float* out     = (float*)d_out;
    float* H_adapt = out;                       // 16*2048*512 = 16,777,216
    float* D_pred  = out + 16777216;            // 16*512 = 8192
    float* P_pred  = out + 16785408;            // 16*2048 = 32768
    float* E_pred  = out + 16818176;            // 16*2048 = 32768

    // ws_size is call-invariant, so this layout choice is graph-stable.
    const bool par = ws_size >= 94000000ull;    // parallel-ep plan needs ~89.1 MiB

    char* ws = (char*)d_ws;
    size_t off = 0;
    unsigned short* wpack = (unsigned short*)(ws + off); off += 6UL * 786432UL * 2UL;  // 9.4 MB
    unsigned short* Hbf   = (unsigned short*)(ws + off); off += 4194304UL * 2UL;       // 8 MB
    unsigned short* h1a   = (unsigned short*)(ws + off); off += 16777216UL * 2UL;      // 33.5 MB (pp)
    unsigned short* h1b   = par ? (unsigned short*)(ws + off) : h1a;                   // ep
    if (par) off += 16777216UL * 2UL;
    unsigned short* h1dp  = (unsigned short*)(ws + off); off += 4194304UL * 2UL;       // 8 MB
    unsigned short* zrow  = (unsigned short*)(ws + off); off += 512UL * 2UL;
    off = (off + 255) & ~(size_t)255;
    int* ridx_exp = (int*)(ws + off); off += (size_t)B_ * T_ * 4;

    hipLaunchKernelGGL(prep_kernel, dim3(10546), dim3(256), 0, stream,
                       dp_w1, dp_w2, pp_w1, pp_w2, ep_w1, ep_w2, wpack, H, Hbf, zrow,
                       Dgt, ridx_exp, D_pred, P_pred, E_pred, dp_bl, pp_bl, ep_bl);

    ConvJob j_pp1 = { Hbf,  ridx_exp, 11,  9, wpack + 2UL * 786432, pp_b1, nullptr, h1a,    8 };
    ConvJob j_ep1 = { Hbf,  ridx_exp, 11,  9, wpack + 4UL * 786432, ep_b1, nullptr, h1b,    8 };
    ConvJob j_dp1 = { Hbf,  nullptr,   9,  9, wpack + 0UL * 786432, dp_b1, nullptr, h1dp,   6 };
    ConvJob j_pp2 = { h1a,  nullptr,  11, 11, wpack + 3UL * 786432, pp_b2, pp_wl,  P_pred, 8 };
    ConvJob j_ep2 = { h1b,  nullptr,  11, 11, wpack + 5UL * 786432, ep_b2, ep_wl,  E_pred, 8 };
    ConvJob j_dp2 = { h1dp, nullptr,   9,  9, wpack + 1UL * 786432, dp_b2, dp_wl,  D_pred, 6 };

    if (par) {
        // conv1 for all three predictors + adapt blocks appended (2048)
        hipLaunchKernelGGL(mega_kernel, dim3(2304 + 2048), dim3(256), 0, stream,
                           j_pp1, j_ep1, j_dp1, 1024, 2048, 2304, 0, zrow,
                           H, ridx_exp, Pgt, Egt, pitch_w, pitch_b, energy_w, energy_b, H_adapt);
        // conv2 + fused final linear for all three
        hipLaunchKernelGGL(mega_kernel, dim3(2304), dim3(256), 0, stream,
                           j_pp2, j_ep2, j_dp2, 1024, 2048, 2304, 1, zrow,
                           H, ridx_exp, Pgt, Egt, pitch_w, pitch_b, energy_w, energy_b, H_adapt);
    } else {
        // serialized ep (h1b aliases h1a): pp+dp first (+adapt), then ep
        hipLaunchKernelGGL(mega_kernel, dim3(1280 + 2048), dim3(256), 0, stream,
                           j_pp1, j_dp1, j_dp1, 1024, 1280, 1280, 0, zrow,
                           H, ridx_exp, Pgt, Egt, pitch_w, pitch_b, energy_w, energy_b, H_adapt);
        hipLaunchKernelGGL(mega_kernel, dim3(1280), dim3(256), 0, stream,
                           j_pp2, j_dp2, j_dp2, 1024, 1280, 1280, 1, zrow,
                           H, ridx_exp, Pgt, Egt, pitch_w, pitch_b, energy_w, energy_b, H_adapt);
        hipLaunchKernelGGL(mega_kernel, dim3(1024), dim3(256), 0, stream,
                           j_ep1, j_ep1, j_ep1, 1024, 1024, 1024, 0, zrow,
                           H, ridx_exp, Pgt, Egt, pitch_w, pitch_b, energy_w, energy_b, H_adapt);
        hipLaunchKernelGGL(mega_kernel, dim3(1024), dim3(256), 0, stream,
                           j_ep2, j_ep2, j_ep2, 1024, 1024, 1024, 1, zrow,
                           H, ridx_exp, Pgt, Egt, pitch_w, pitch_b, energy_w, energy_b, H_adapt);
    }
}